// Round 2
// 479.107 us; speedup vs baseline: 1.0004x; 1.0004x over previous
//
#include <hip/hip_runtime.h>

#define BB 16
#define RR 64
#define SS 128
#define MM 64
#define LL 128
#define EE 4032

// out layout (fp32, concatenated):
// inc_add [16*64*128 = 131072] | inc_gain [131072] |
// mean_s [16*64*64*64 = 4194304] | logstd_s [4194304] | msg_s [4194304]
#define OUT3_OFF 262144
#define ARR_SZ   4194304

// ---------------------------------------------------------------------------
// Zero the scatter-add targets and the diagonal (s==t) blocks of the three
// scattered outputs (d_out is re-poisoned to 0xAA before every launch).
// 262144 + 3*65536 = 458752 elements -> 1792 blocks x 256 exactly.
// ---------------------------------------------------------------------------
__global__ __launch_bounds__(256) void k_zero(float* __restrict__ out) {
  int tid = blockIdx.x * 256 + threadIdx.x;
  if (tid < 262144) { out[tid] = 0.0f; return; }
  int idx = tid - 262144;          // < 196608
  int a = idx >> 16;               // which of the 3 scattered arrays
  int r = idx & 65535;
  int b = r >> 12;                 // batch
  int d = (r >> 6) & 63;           // diagonal index
  int m = r & 63;
  out[OUT3_OFF + (size_t)a * ARR_SZ + (size_t)b * 262144 + d * 4160 + m] = 0.0f;
}

// ---------------------------------------------------------------------------
// One block per edge: mean/logstd GEMMs + scatter-set of mean/logstd/msg.
// Thread t: m = t>>2, sq = t&3 (s-quarter, interleaved 16-float strips so
// LDS reads are conflict-free broadcasts with src row stride 132).
// v2: depth-3 rotating register prefetch of the weight float4s — the old
// load-then-FMA-per-k structure left only ~2 loads in flight per wave
// (latency-bound at 1.65 TB/s). Prefetching k+2 while consuming k keeps
// 4-6 loads outstanding per wave.
// ---------------------------------------------------------------------------
__global__ __launch_bounds__(256) void k_edge(
    const float* __restrict__ source,
    const float* __restrict__ mean_w,
    const float* __restrict__ mean_b,
    const float* __restrict__ logstd_w,
    const float* __restrict__ logstd_b,
    const int* __restrict__ src_idx,
    const int* __restrict__ tgt_idx,
    float* __restrict__ out)
{
  __shared__ float lds_src[BB * 132];     // 16 rows of 128, stride 132
  __shared__ float lds_mean[BB * 64];
  __shared__ float lds_logstd[BB * 64];
  const int e = blockIdx.x;
  const int tid = threadIdx.x;
  const int sidx = src_idx[e];
  const int tidx = tgt_idx[e];

  // stage source[:, sidx, :] (16 x 128 floats = 512 float4)
  #pragma unroll
  for (int f0 = 0; f0 < 2; ++f0) {
    int f = tid + f0 * 256;
    int b = f >> 5, s4 = f & 31;
    float4 v = *(const float4*)(source + ((size_t)b * (RR * SS) + (size_t)sidx * SS + s4 * 4));
    *(float4*)(lds_src + b * 132 + s4 * 4) = v;
  }

  const int m = tid >> 2;   // 0..63
  const int sq = tid & 3;   // s-quarter

  const float* wmp = mean_w   + ((size_t)e * (MM * SS) + (size_t)m * SS) + sq * 4;
  const float* wlp = logstd_w + ((size_t)e * (MM * SS) + (size_t)m * SS) + sq * 4;

  // prologue: issue chunks k=0,1 before the barrier (overlap with src staging)
  float4 a0 = *(const float4*)(wmp + 0);
  float4 c0 = *(const float4*)(wlp + 0);
  float4 a1 = *(const float4*)(wmp + 16);
  float4 c1 = *(const float4*)(wlp + 16);

  __syncthreads();

  float accm[BB], accl[BB];
  #pragma unroll
  for (int b = 0; b < BB; ++b) { accm[b] = 0.0f; accl[b] = 0.0f; }

  #pragma unroll
  for (int k = 0; k < 8; ++k) {
    float4 a2 = {}, c2 = {};
    if (k < 6) {                        // issue chunk k+2 (in flight across consume)
      a2 = *(const float4*)(wmp + (k + 2) * 16);
      c2 = *(const float4*)(wlp + (k + 2) * 16);
    }
    const int soff = sq * 4 + k * 16;   // interleaved strips: conflict-free LDS
    #pragma unroll
    for (int b = 0; b < BB; ++b) {
      float4 sv = *(const float4*)(lds_src + b * 132 + soff);
      accm[b] = fmaf(a0.x, sv.x, fmaf(a0.y, sv.y, fmaf(a0.z, sv.z, fmaf(a0.w, sv.w, accm[b]))));
      accl[b] = fmaf(c0.x, sv.x, fmaf(c0.y, sv.y, fmaf(c0.z, sv.z, fmaf(c0.w, sv.w, accl[b]))));
    }
    a0 = a1; c0 = c1; a1 = a2; c1 = c2; // rotate (renamed away by full unroll)
  }
  // reduce the 4 s-quarters (adjacent lanes) — all 4 lanes end with full sums
  #pragma unroll
  for (int b = 0; b < BB; ++b) {
    accm[b] += __shfl_xor(accm[b], 1);
    accm[b] += __shfl_xor(accm[b], 2);
    accl[b] += __shfl_xor(accl[b], 1);
    accl[b] += __shfl_xor(accl[b], 2);
  }
  const float bm = mean_b[e * MM + m];
  const float bl = logstd_b[e * MM + m];
  #pragma unroll
  for (int j = 0; j < 4; ++j) {
    int b = sq * 4 + j;                 // each lane writes 4 distinct batches
    lds_mean[b * 64 + m]   = accm[b] + bm;
    lds_logstd[b * 64 + m] = accl[b] + bl;
  }
  __syncthreads();

  // coalesced 256B-segment scatter-set writes: msg == mean (deterministic path)
  float* out3 = out + OUT3_OFF;
  float* out4 = out3 + ARR_SZ;
  float* out5 = out4 + ARR_SZ;
  const size_t rowbase = (size_t)(sidx * RR + tidx) * MM;
  const int b = tid >> 4, m4 = tid & 15;
  float4 vm = *(float4*)(lds_mean + b * 64 + m4 * 4);
  float4 vl = *(float4*)(lds_logstd + b * 64 + m4 * 4);
  size_t o = (size_t)b * (RR * RR * MM) + rowbase + m4 * 4;
  *(float4*)(out3 + o) = vm;
  *(float4*)(out4 + o) = vl;
  *(float4*)(out5 + o) = vm;
}

// ---------------------------------------------------------------------------
// Scatter-add stage: grid = 64 tgt x 2 l-halves x 9 s-chunks (7 edges each).
// v2: one-step-ahead register prefetch of the 8 weight float4s + the mean
// tile float4, double-buffered LDS mean tile, ONE __syncthreads per step.
// The j+1 loads are issued right after the barrier and consumed one full
// FMA phase later, so the barrier's vmcnt(0) drain finds them landed.
// ---------------------------------------------------------------------------
__global__ __launch_bounds__(256) void k_inc(
    const float* __restrict__ add_w,
    const float* __restrict__ gain_w,
    float* __restrict__ out)
{
  __shared__ float lds_mean[2][BB * 64];
  const int g = blockIdx.x;        // 64*2*9 = 1152
  const int tt = g / 18;
  const int r = g % 18;
  const int lh = r / 9;
  const int c = r % 9;
  const int tid = threadIdx.x;
  const int l_loc = tid >> 2;      // 0..63
  const int mq = tid & 3;          // m-quarter
  const int l = lh * 64 + l_loc;
  const int b16 = tid >> 4, m4 = tid & 15;

  const float* out3 = out + OUT3_OFF;

  float acca[BB], accg[BB];
  #pragma unroll
  for (int b = 0; b < BB; ++b) { acca[b] = 0.0f; accg[b] = 0.0f; }

  // prologue prefetch: step j=0
  float4 mv_n;
  float4 wa_n[4], wg_n[4];
  {
    const int si = c * 7;
    const int s = si + (si >= tt ? 1 : 0);
    const int e = s * 63 + (tt > s ? tt - 1 : tt);
    mv_n = *(const float4*)(out3 + ((size_t)b16 * 262144 + (size_t)(s * 64 + tt) * 64 + m4 * 4));
    const float* wa = add_w  + ((size_t)e * (LL * MM) + (size_t)l * MM + mq * 16);
    const float* wg = gain_w + ((size_t)e * (LL * MM) + (size_t)l * MM + mq * 16);
    #pragma unroll
    for (int i = 0; i < 4; ++i) {
      wa_n[i] = *(const float4*)(wa + i * 4);
      wg_n[i] = *(const float4*)(wg + i * 4);
    }
  }

  #pragma unroll
  for (int j = 0; j < 7; ++j) {
    // rotate next -> current (renames after full unroll)
    float4 mv = mv_n;
    float4 wa_c[4], wg_c[4];
    #pragma unroll
    for (int i = 0; i < 4; ++i) { wa_c[i] = wa_n[i]; wg_c[i] = wg_n[i]; }

    *(float4*)(&lds_mean[j & 1][b16 * 64 + m4 * 4]) = mv;
    __syncthreads();   // publishes tile j; buffer (j&1) was last read at step j-2

    if (j < 6) {       // issue step j+1 loads: 9 in flight across the FMA phase
      const int si2 = c * 7 + j + 1;
      const int s2 = si2 + (si2 >= tt ? 1 : 0);
      const int e2 = s2 * 63 + (tt > s2 ? tt - 1 : tt);
      mv_n = *(const float4*)(out3 + ((size_t)b16 * 262144 + (size_t)(s2 * 64 + tt) * 64 + m4 * 4));
      const float* wa2 = add_w  + ((size_t)e2 * (LL * MM) + (size_t)l * MM + mq * 16);
      const float* wg2 = gain_w + ((size_t)e2 * (LL * MM) + (size_t)l * MM + mq * 16);
      #pragma unroll
      for (int i = 0; i < 4; ++i) {
        wa_n[i] = *(const float4*)(wa2 + i * 4);
        wg_n[i] = *(const float4*)(wg2 + i * 4);
      }
    }

    #pragma unroll
    for (int i = 0; i < 4; ++i) {
      float4 a  = wa_c[i];
      float4 gq = wg_c[i];
      #pragma unroll
      for (int b = 0; b < BB; ++b) {
        float4 mvv = *(const float4*)(&lds_mean[j & 1][b * 64 + mq * 16 + i * 4]);
        acca[b] = fmaf(a.x,  mvv.x, fmaf(a.y,  mvv.y, fmaf(a.z,  mvv.z, fmaf(a.w,  mvv.w, acca[b]))));
        accg[b] = fmaf(gq.x, mvv.x, fmaf(gq.y, mvv.y, fmaf(gq.z, mvv.z, fmaf(gq.w, mvv.w, accg[b]))));
      }
    }
  }
  // reduce the 4 m-quarters (adjacent lanes)
  #pragma unroll
  for (int b = 0; b < BB; ++b) {
    acca[b] += __shfl_xor(acca[b], 1);
    acca[b] += __shfl_xor(acca[b], 2);
    accg[b] += __shfl_xor(accg[b], 1);
    accg[b] += __shfl_xor(accg[b], 2);
  }
  float* inc_add  = out;
  float* inc_gain = out + 131072;
  #pragma unroll
  for (int jj = 0; jj < 4; ++jj) {
    int b = mq * 4 + jj;                      // each lane commits 4 batches
    size_t o = (size_t)b * (RR * LL) + (size_t)tt * LL + l;
    atomicAdd(inc_add + o, acca[b]);
    atomicAdd(inc_gain + o, accg[b]);
  }
}

extern "C" void kernel_launch(void* const* d_in, const int* in_sizes, int n_in,
                              void* d_out, int out_size, void* d_ws, size_t ws_size,
                              hipStream_t stream) {
  const float* source   = (const float*)d_in[0];
  const float* mean_w   = (const float*)d_in[1];
  const float* mean_b   = (const float*)d_in[2];
  const float* logstd_w = (const float*)d_in[3];
  const float* logstd_b = (const float*)d_in[4];
  const float* add_w    = (const float*)d_in[5];
  const float* gain_w   = (const float*)d_in[6];
  const int*   src_idx  = (const int*)d_in[7];
  const int*   tgt_idx  = (const int*)d_in[8];
  float* out = (float*)d_out;

  k_zero<<<1792, 256, 0, stream>>>(out);
  k_edge<<<EE, 256, 0, stream>>>(source, mean_w, mean_b, logstd_w, logstd_b,
                                 src_idx, tgt_idx, out);
  k_inc<<<1152, 256, 0, stream>>>(add_w, gain_w, out);
}